// Round 7
// baseline (446.950 us; speedup 1.0000x reference)
//
#include <hip/hip_runtime.h>
#include <hip/hip_bf16.h>

// ---------- types & helpers ----------
typedef __bf16 bf16x8 __attribute__((ext_vector_type(8)));
typedef float f32x4 __attribute__((ext_vector_type(4)));
typedef float f32x16 __attribute__((ext_vector_type(16)));

__device__ __forceinline__ float bf2f(unsigned short u) {
  union { unsigned int i; float f; } v; v.i = ((unsigned int)u) << 16; return v.f;
}
__device__ __forceinline__ unsigned short f2bf(float f) {
  union { unsigned int i; float f; } v; v.f = f;
  unsigned int i = v.i;
  return (unsigned short)((i + 0x7FFFu + ((i >> 16) & 1u)) >> 16);  // RNE
}

// async global->LDS, 16B per lane; LDS dest = wave-uniform base + lane*16
typedef const __attribute__((address_space(1))) unsigned int* gas_ptr;
typedef __attribute__((address_space(3))) unsigned int* las_ptr;
__device__ __forceinline__ void gload_lds16(const unsigned short* g, unsigned short* l) {
  __builtin_amdgcn_global_load_lds((gas_ptr)(const void*)g, (las_ptr)(void*)l, 16, 0, 0);
}

// ---------- dtype detection: flag=1 if input is bf16, 0 if fp32 ----------
__global__ __launch_bounds__(256) void detect_k(const unsigned short* __restrict__ h,
                                                int* __restrict__ flag) {
  __shared__ int s[256];
  int cnt = 0;
  for (int i = threadIdx.x; i < 4096; i += 256) {
    unsigned short u = h[2 * i];
    int e = (u >> 7) & 0xFF;
    if ((e >= 96 && e <= 140) || u == 0) cnt++;
  }
  s[threadIdx.x] = cnt;
  __syncthreads();
  for (int o = 128; o > 0; o >>= 1) {
    if (threadIdx.x < o) s[threadIdx.x] += s[threadIdx.x + o];
    __syncthreads();
  }
  if (threadIdx.x == 0) *flag = (s[0] >= 3600) ? 1 : 0;
}

// ---------- convert (fp32->bf16 or copy) ----------
__global__ __launch_bounds__(256) void cvt_k(const void* __restrict__ src,
                                             unsigned short* __restrict__ dst, int n,
                                             const int* __restrict__ flag) {
  const int f = *flag;
  for (int i = blockIdx.x * 256 + threadIdx.x; i < n; i += gridDim.x * 256)
    dst[i] = f ? ((const unsigned short*)src)[i] : f2bf(((const float*)src)[i]);
}

// ---------- transpose + convert: dst[c][r] = bf16(src[r][c]) ----------
__global__ __launch_bounds__(256) void transpose_cvt_k(const void* __restrict__ src,
                                                       unsigned short* __restrict__ dst,
                                                       int R, int C,
                                                       const int* __restrict__ flag) {
  __shared__ unsigned short tile[32][33];
  const int f = *flag;
  const int x = threadIdx.x & 31;
  const int y = threadIdx.x >> 5;  // 0..7
  const int r0 = blockIdx.y * 32, c0 = blockIdx.x * 32;
#pragma unroll
  for (int i = 0; i < 4; i++) {
    size_t idx = (size_t)(r0 + y + 8 * i) * C + c0 + x;
    tile[y + 8 * i][x] = f ? ((const unsigned short*)src)[idx]
                           : f2bf(((const float*)src)[idx]);
  }
  __syncthreads();
#pragma unroll
  for (int i = 0; i < 4; i++)
    dst[(size_t)(c0 + y + 8 * i) * R + r0 + x] = tile[x][y + 8 * i];
}

// ---------- V pre-transpose: Vt[(b*16+h)*128+d][key] ----------
__global__ __launch_bounds__(256) void transpose_v_k(const unsigned short* __restrict__ qkv,
                                                     unsigned short* __restrict__ Vt) {
  __shared__ unsigned short tile[32][33];
  const int bh = blockIdx.z;              // b*16+h
  const int b = bh >> 4, hh = bh & 15;
  const int s0 = blockIdx.x * 32, d0 = blockIdx.y * 32;
  const int x = threadIdx.x & 31, y = threadIdx.x >> 5;
#pragma unroll
  for (int i = 0; i < 4; i++)
    tile[y + 8 * i][x] =
        qkv[((size_t)b * 2048 + s0 + y + 8 * i) * 6144 + 4096 + hh * 128 + d0 + x];
  __syncthreads();
#pragma unroll
  for (int i = 0; i < 4; i++)
    Vt[((size_t)bh * 128 + d0 + y + 8 * i) * 2048 + s0 + x] = tile[x][y + 8 * i];
}

// ---------- GEMM 128x128 tile: global_load_lds staging + XOR-swizzled LDS ----------
// (round-6 winner: 854 TF, zero bank conflicts — unchanged)
__global__ __launch_bounds__(256) void gemm_bias_k(const unsigned short* __restrict__ A,
                                                   const unsigned short* __restrict__ Bt,
                                                   const unsigned short* __restrict__ bias,
                                                   void* __restrict__ Cout,
                                                   int M, int N, int K,
                                                   const int* __restrict__ flag,
                                                   int final_out) {
  __shared__ __attribute__((aligned(16))) unsigned short As[128][64];
  __shared__ __attribute__((aligned(16))) unsigned short Bs[128][64];
  const int t = threadIdx.x;
  const int wave = t >> 6, lane = t & 63;
  const int col = lane & 15, quad = lane >> 4;
  const int wm = wave >> 1, wn = wave & 1;
  const int m0 = blockIdx.y * 128, n0 = blockIdx.x * 128;
  const int srow = lane >> 3;                       // row within 8-row segment
  const int schunk = ((lane & 7) ^ srow) * 8;       // swizzled source chunk (shorts)
  const int rsw = col & 7;                          // read-side swizzle key

  const f32x4 fzero = {0.f, 0.f, 0.f, 0.f};
  f32x4 acc[4][4];
#pragma unroll
  for (int i = 0; i < 4; i++)
#pragma unroll
    for (int j = 0; j < 4; j++) acc[i][j] = fzero;

  for (int k0 = 0; k0 < K; k0 += 64) {
    __syncthreads();
#pragma unroll
    for (int c = 0; c < 4; c++) {
      int seg = wave * 4 + c;          // 16 segments of 8 rows
      int row = seg * 8 + srow;
      gload_lds16(&A [(size_t)(m0 + row) * K + k0 + schunk], &As[seg * 8][0]);
      gload_lds16(&Bt[(size_t)(n0 + row) * K + k0 + schunk], &Bs[seg * 8][0]);
    }
    __syncthreads();  // drains vmcnt
#pragma unroll
    for (int ks = 0; ks < 2; ks++) {
      bf16x8 af[4], bfr[4];
#pragma unroll
      for (int i = 0; i < 4; i++)
        af[i] = *(const bf16x8*)&As[wm * 64 + i * 16 + col][(((ks << 2) | quad) ^ rsw) * 8];
#pragma unroll
      for (int j = 0; j < 4; j++)
        bfr[j] = *(const bf16x8*)&Bs[wn * 64 + j * 16 + col][(((ks << 2) | quad) ^ rsw) * 8];
#pragma unroll
      for (int i = 0; i < 4; i++)
#pragma unroll
        for (int j = 0; j < 4; j++)
          acc[i][j] = __builtin_amdgcn_mfma_f32_16x16x32_bf16(af[i], bfr[j], acc[i][j], 0, 0, 0);
    }
  }
  const int f32o = final_out ? (*flag == 0) : 0;
#pragma unroll
  for (int j = 0; j < 4; j++) {
    int n = n0 + wn * 64 + j * 16 + col;
    float bv = bf2f(bias[n]);
#pragma unroll
    for (int i = 0; i < 4; i++)
#pragma unroll
      for (int r = 0; r < 4; r++) {
        int m = m0 + wm * 64 + i * 16 + quad * 4 + r;
        float v = acc[i][j][r] + bv;
        if (f32o) ((float*)Cout)[(size_t)m * N + n] = v;
        else      ((unsigned short*)Cout)[(size_t)m * N + n] = f2bf(v);
      }
  }
}

// ---------- flash attention (causal), 32x32x16 MFMA, chunk-planar LDS ----------
// Q-tile 128 rows (4 waves x 32), K-tile 64 keys. Block x in [0,8) runs
// qt = 15-x then qt = x -> 34 iterations each, fully balanced (256 blocks).
// A/B frag: m|n = lane&31, k = (lane>>5)*8+j. C/D: col=lane&31,
// row = (reg&3)+8*(reg>>2)+4*(lane>>5)  [m74/m101].
// LDS chunk-planar [chunk][row][8]: every b128 frag read is 32x16B contiguous
// -> conflict-free.
#define ATT_SCALE 0.08838834764831845f  // 1/sqrt(128)
__global__ __launch_bounds__(256) void attn_k(const unsigned short* __restrict__ qkv,
                                              const unsigned short* __restrict__ Vt,
                                              unsigned short* __restrict__ O) {
  __shared__ __attribute__((aligned(16))) unsigned short Ks2[16][64][8];   // [d-chunk][key][8]
  __shared__ __attribute__((aligned(16))) unsigned short Vs2[8][128][8];   // [key-chunk][d][8]
  __shared__ __attribute__((aligned(16))) unsigned short Ps2[4][8][32][8]; // [w][key-chunk][row][8]
  const int t = threadIdx.x;
  const int wave = t >> 6, lane = t & 63;
  const int l31 = lane & 31, hw = lane >> 5;
  const int h = blockIdx.y, b = blockIdx.z;
  const size_t base = (size_t)b * 2048 * 6144;
  const size_t vbase = ((size_t)(b * 16 + h)) * 128 * 2048;
  const int hcol = h * 128;

  const int kr = t >> 2;        // K staging: key row 0..63
  const int kc = (t & 3) * 8;   // d offset 0/8/16/24 (+p*32)
  const int vr = t >> 1;        // V staging: d row 0..127
  const int vc = (t & 1) * 32;  // key offset 0/32

  for (int pass = 0; pass < 2; pass++) {
    const int qt = pass ? (int)blockIdx.x : 15 - (int)blockIdx.x;
    const int nkt = 2 * qt + 2;
    const int qrow0 = qt * 128 + wave * 32;  // wave's first q-row (absolute)

    bf16x8 qf[8];  // Q A-frags: m=l31, d = ks*16 + hw*8 + j
    {
      size_t qrow = base + (size_t)(qrow0 + l31) * 6144 + hcol;
#pragma unroll
      for (int ks = 0; ks < 8; ks++)
        qf[ks] = *(const bf16x8*)&qkv[qrow + ks * 16 + hw * 8];
    }

    f32x16 o[4];
#pragma unroll
    for (int i = 0; i < 4; i++)
#pragma unroll
      for (int r = 0; r < 16; r++) o[i][r] = 0.f;
    float l_acc[16];
#pragma unroll
    for (int r = 0; r < 16; r++) l_acc[r] = 0.f;

    __syncthreads();  // guard LDS vs previous pass readers
    {  // stage tile kt=0
      size_t grow = base + (size_t)kr * 6144 + 2048 + hcol;
#pragma unroll
      for (int p = 0; p < 4; p++)
        *(bf16x8*)&Ks2[(kc >> 3) + p * 4][kr][0] = *(const bf16x8*)&qkv[grow + kc + p * 32];
      size_t vrow = vbase + (size_t)vr * 2048;
#pragma unroll
      for (int c = 0; c < 4; c++)
        *(bf16x8*)&Vs2[(vc >> 3) + c][vr][0] = *(const bf16x8*)&Vt[vrow + vc + c * 8];
    }
    __syncthreads();

    for (int kt = 0; kt < nkt; kt++) {
      // register prefetch of tile kt+1
      bf16x8 kreg[4], vreg[4];
      const bool pf = (kt + 1 < nkt);
      if (pf) {
        size_t grow = base + (size_t)((kt + 1) * 64 + kr) * 6144 + 2048 + hcol;
#pragma unroll
        for (int p = 0; p < 4; p++)
          kreg[p] = *(const bf16x8*)&qkv[grow + kc + p * 32];
        size_t vrow = vbase + (size_t)vr * 2048 + (kt + 1) * 64;
#pragma unroll
        for (int c = 0; c < 4; c++)
          vreg[c] = *(const bf16x8*)&Vt[vrow + vc + c * 8];
      }

      // skip waves whose whole 32x64 score tile is causally masked
      const bool active = (kt * 64 < qrow0 + 32);
      if (active) {
        // S = Q @ K^T : 2 key-blocks x 8 k-steps of 16
        f32x16 sc[2];
#pragma unroll
        for (int nb = 0; nb < 2; nb++)
#pragma unroll
          for (int r = 0; r < 16; r++) sc[nb][r] = 0.f;
#pragma unroll
        for (int ks = 0; ks < 8; ks++)
#pragma unroll
          for (int nb = 0; nb < 2; nb++) {
            bf16x8 kf = *(const bf16x8*)&Ks2[ks * 2 + hw][nb * 32 + l31][0];
            sc[nb] = __builtin_amdgcn_mfma_f32_32x32x16_bf16(qf[ks], kf, sc[nb], 0, 0, 0);
          }

        // p = exp(scale*s) with causal mask; accumulate l; write P to LDS
#pragma unroll
        for (int nb = 0; nb < 2; nb++) {
          const int key = kt * 64 + nb * 32 + l31;
#pragma unroll
          for (int r = 0; r < 16; r++) {
            const int row = (r & 3) + 8 * (r >> 2) + 4 * hw;
            float p = (key <= qrow0 + row) ? __expf(sc[nb][r] * ATT_SCALE) : 0.f;
            l_acc[r] += p;
            Ps2[wave][nb * 4 + (l31 >> 3)][row][l31 & 7] = f2bf(p);
          }
        }
        // O += P @ V^T : 4 d-blocks x 4 k-steps of 16 (same-wave LDS roundtrip)
#pragma unroll
        for (int ks2 = 0; ks2 < 4; ks2++) {
          bf16x8 pa = *(const bf16x8*)&Ps2[wave][ks2 * 2 + hw][l31][0];
#pragma unroll
          for (int nbo = 0; nbo < 4; nbo++) {
            bf16x8 vf = *(const bf16x8*)&Vs2[ks2 * 2 + hw][nbo * 32 + l31][0];
            o[nbo] = __builtin_amdgcn_mfma_f32_32x32x16_bf16(pa, vf, o[nbo], 0, 0, 0);
          }
        }
      }

      __syncthreads();  // all waves done reading Ks2/Vs2
      if (pf) {
#pragma unroll
        for (int p = 0; p < 4; p++)
          *(bf16x8*)&Ks2[(kc >> 3) + p * 4][kr][0] = kreg[p];
#pragma unroll
        for (int c = 0; c < 4; c++)
          *(bf16x8*)&Vs2[(vc >> 3) + c][vr][0] = vreg[c];
      }
      __syncthreads();  // staged tile visible
    }

    // deferred l reduction over the 32 lanes of this half (keys)
#pragma unroll
    for (int r = 0; r < 16; r++) {
#pragma unroll
      for (int off = 1; off < 32; off <<= 1)
        l_acc[r] += __shfl_xor(l_acc[r], off, 64);
      l_acc[r] = 1.0f / l_acc[r];
    }

    // store O (row = C/D mapping), coalesced b16 across l31
#pragma unroll
    for (int nbo = 0; nbo < 4; nbo++)
#pragma unroll
      for (int r = 0; r < 16; r++) {
        const int row = (r & 3) + 8 * (r >> 2) + 4 * hw;
        O[((size_t)b * 2048 + qrow0 + row) * 2048 + hcol + nbo * 32 + l31] =
            f2bf(o[nbo][r] * l_acc[r]);
      }
  }
}

// ---------- launch ----------
extern "C" void kernel_launch(void* const* d_in, const int* in_sizes, int n_in,
                              void* d_out, int out_size, void* d_ws, size_t ws_size,
                              hipStream_t stream) {
  (void)in_sizes; (void)n_in; (void)out_size; (void)ws_size;
  int* flag = (int*)d_ws;
  unsigned short* wsu = (unsigned short*)d_ws + 128;
  unsigned short* Wt_qkv    = wsu;                                  // 6144*2048
  unsigned short* Wt_proj   = Wt_qkv + (size_t)6144 * 2048;         // 2048*2048
  unsigned short* QKV       = Wt_proj + (size_t)2048 * 2048;        // 4096*6144
  unsigned short* hidden_bf = QKV + (size_t)4096 * 6144;            // 4096*2048
  unsigned short* bias_q    = hidden_bf + (size_t)4096 * 2048;      // 6144
  unsigned short* bias_p    = bias_q + 6144;                        // 2048
  unsigned short* Obuf      = Wt_qkv;     // alias: dead after QKV gemm
  unsigned short* Vt        = hidden_bf;  // alias: dead after QKV gemm

  detect_k<<<1, 256, 0, stream>>>((const unsigned short*)d_in[0], flag);
  cvt_k<<<4096, 256, 0, stream>>>(d_in[0], hidden_bf, 4096 * 2048, flag);
  cvt_k<<<24, 256, 0, stream>>>(d_in[2], bias_q, 6144, flag);
  cvt_k<<<8, 256, 0, stream>>>(d_in[4], bias_p, 2048, flag);
  transpose_cvt_k<<<dim3(192, 64), 256, 0, stream>>>(d_in[1], Wt_qkv, 2048, 6144, flag);
  transpose_cvt_k<<<dim3(64, 64), 256, 0, stream>>>(d_in[3], Wt_proj, 2048, 2048, flag);
  gemm_bias_k<<<dim3(48, 32), 256, 0, stream>>>(hidden_bf, Wt_qkv, bias_q, QKV,
                                                4096, 6144, 2048, flag, 0);
  transpose_v_k<<<dim3(64, 4, 32), 256, 0, stream>>>(QKV, Vt);
  attn_k<<<dim3(8, 16, 2), 256, 0, stream>>>(QKV, Vt, Obuf);
  gemm_bias_k<<<dim3(16, 32), 256, 0, stream>>>(Obuf, Wt_proj, bias_p, d_out,
                                                4096, 2048, 2048, flag, 1);
}

// Round 8
// 417.437 us; speedup vs baseline: 1.0707x; 1.0707x over previous
//
#include <hip/hip_runtime.h>
#include <hip/hip_bf16.h>

// ---------- types & helpers ----------
typedef __bf16 bf16x8 __attribute__((ext_vector_type(8)));
typedef float f32x4 __attribute__((ext_vector_type(4)));

__device__ __forceinline__ float bf2f(unsigned short u) {
  union { unsigned int i; float f; } v; v.i = ((unsigned int)u) << 16; return v.f;
}
__device__ __forceinline__ unsigned short f2bf(float f) {
  union { unsigned int i; float f; } v; v.f = f;
  unsigned int i = v.i;
  return (unsigned short)((i + 0x7FFFu + ((i >> 16) & 1u)) >> 16);  // RNE
}

// async global->LDS, 16B per lane; LDS dest = wave-uniform base + lane*16
typedef const __attribute__((address_space(1))) unsigned int* gas_ptr;
typedef __attribute__((address_space(3))) unsigned int* las_ptr;
__device__ __forceinline__ void gload_lds16(const unsigned short* g, unsigned short* l) {
  __builtin_amdgcn_global_load_lds((gas_ptr)(const void*)g, (las_ptr)(void*)l, 16, 0, 0);
}

// ---------- dtype detection: flag=1 if input is bf16, 0 if fp32 ----------
__global__ __launch_bounds__(256) void detect_k(const unsigned short* __restrict__ h,
                                                int* __restrict__ flag) {
  __shared__ int s[256];
  int cnt = 0;
  for (int i = threadIdx.x; i < 4096; i += 256) {
    unsigned short u = h[2 * i];
    int e = (u >> 7) & 0xFF;
    if ((e >= 96 && e <= 140) || u == 0) cnt++;
  }
  s[threadIdx.x] = cnt;
  __syncthreads();
  for (int o = 128; o > 0; o >>= 1) {
    if (threadIdx.x < o) s[threadIdx.x] += s[threadIdx.x + o];
    __syncthreads();
  }
  if (threadIdx.x == 0) *flag = (s[0] >= 3600) ? 1 : 0;
}

// ---------- hidden cvt: only needed for fp32 inputs; early-exit when bf16 ----------
__global__ __launch_bounds__(256) void cvt_hidden_k(const void* __restrict__ src,
                                                    unsigned short* __restrict__ dst, int n,
                                                    const int* __restrict__ flag) {
  if (*flag) return;  // bf16 input: GEMM reads d_in[0] directly
  for (int i = blockIdx.x * 256 + threadIdx.x; i < n; i += gridDim.x * 256)
    dst[i] = f2bf(((const float*)src)[i]);
}

// ---------- fused weight transpose+convert (both weights, one launch) ----------
// blocks [0, 12288): W_qkv [2048,6144] -> Wt_qkv [6144,2048]  (192 x 64 tiles)
// blocks [12288, 16384): W_proj [2048,2048] -> Wt_proj        (64 x 64 tiles)
__global__ __launch_bounds__(256) void transpose_w2_k(const void* __restrict__ w_qkv,
                                                      const void* __restrict__ w_proj,
                                                      unsigned short* __restrict__ dst_qkv,
                                                      unsigned short* __restrict__ dst_proj,
                                                      const int* __restrict__ flag) {
  __shared__ unsigned short tile[32][33];
  const int f = *flag;
  int bid = blockIdx.x;
  const void* src;
  unsigned short* dst;
  int R = 2048, C, cx, cy;
  if (bid < 12288) {
    src = w_qkv; dst = dst_qkv; C = 6144; cx = bid % 192; cy = bid / 192;
  } else {
    bid -= 12288;
    src = w_proj; dst = dst_proj; C = 2048; cx = bid % 64; cy = bid / 64;
  }
  const int x = threadIdx.x & 31;
  const int y = threadIdx.x >> 5;  // 0..7
  const int r0 = cy * 32, c0 = cx * 32;
#pragma unroll
  for (int i = 0; i < 4; i++) {
    size_t idx = (size_t)(r0 + y + 8 * i) * C + c0 + x;
    tile[y + 8 * i][x] = f ? ((const unsigned short*)src)[idx]
                           : f2bf(((const float*)src)[idx]);
  }
  __syncthreads();
#pragma unroll
  for (int i = 0; i < 4; i++)
    dst[(size_t)(c0 + y + 8 * i) * R + r0 + x] = tile[x][y + 8 * i];
}

// ---------- V pre-transpose: Vt[(b*16+h)*128+d][key] ----------
__global__ __launch_bounds__(256) void transpose_v_k(const unsigned short* __restrict__ qkv,
                                                     unsigned short* __restrict__ Vt) {
  __shared__ unsigned short tile[32][33];
  const int bh = blockIdx.z;              // b*16+h
  const int b = bh >> 4, hh = bh & 15;
  const int s0 = blockIdx.x * 32, d0 = blockIdx.y * 32;
  const int x = threadIdx.x & 31, y = threadIdx.x >> 5;
#pragma unroll
  for (int i = 0; i < 4; i++)
    tile[y + 8 * i][x] =
        qkv[((size_t)b * 2048 + s0 + y + 8 * i) * 6144 + 4096 + hh * 128 + d0 + x];
  __syncthreads();
#pragma unroll
  for (int i = 0; i < 4; i++)
    Vt[((size_t)bh * 128 + d0 + y + 8 * i) * 2048 + s0 + x] = tile[x][y + 8 * i];
}

// ---------- GEMM 128x128 tile: global_load_lds staging + XOR-swizzled LDS ----------
// (854 TF, zero bank conflicts). A selected device-side: flag ? A_bf16 : A_cvt.
// Bias read raw (fp32 or bf16 per flag).
__global__ __launch_bounds__(256) void gemm_bias_k(const unsigned short* __restrict__ A_bf,
                                                   const unsigned short* __restrict__ A_cvt,
                                                   const unsigned short* __restrict__ Bt,
                                                   const void* __restrict__ bias,
                                                   void* __restrict__ Cout,
                                                   int M, int N, int K,
                                                   const int* __restrict__ flag,
                                                   int final_out) {
  __shared__ __attribute__((aligned(16))) unsigned short As[128][64];
  __shared__ __attribute__((aligned(16))) unsigned short Bs[128][64];
  const int f = *flag;
  const unsigned short* A = f ? A_bf : A_cvt;
  const int t = threadIdx.x;
  const int wave = t >> 6, lane = t & 63;
  const int col = lane & 15, quad = lane >> 4;
  const int wm = wave >> 1, wn = wave & 1;
  const int m0 = blockIdx.y * 128, n0 = blockIdx.x * 128;
  const int srow = lane >> 3;                       // row within 8-row segment
  const int schunk = ((lane & 7) ^ srow) * 8;       // swizzled source chunk (shorts)
  const int rsw = col & 7;                          // read-side swizzle key

  const f32x4 fzero = {0.f, 0.f, 0.f, 0.f};
  f32x4 acc[4][4];
#pragma unroll
  for (int i = 0; i < 4; i++)
#pragma unroll
    for (int j = 0; j < 4; j++) acc[i][j] = fzero;

  for (int k0 = 0; k0 < K; k0 += 64) {
    __syncthreads();
#pragma unroll
    for (int c = 0; c < 4; c++) {
      int seg = wave * 4 + c;          // 16 segments of 8 rows
      int row = seg * 8 + srow;
      gload_lds16(&A [(size_t)(m0 + row) * K + k0 + schunk], &As[seg * 8][0]);
      gload_lds16(&Bt[(size_t)(n0 + row) * K + k0 + schunk], &Bs[seg * 8][0]);
    }
    __syncthreads();  // drains vmcnt
#pragma unroll
    for (int ks = 0; ks < 2; ks++) {
      bf16x8 af[4], bfr[4];
#pragma unroll
      for (int i = 0; i < 4; i++)
        af[i] = *(const bf16x8*)&As[wm * 64 + i * 16 + col][(((ks << 2) | quad) ^ rsw) * 8];
#pragma unroll
      for (int j = 0; j < 4; j++)
        bfr[j] = *(const bf16x8*)&Bs[wn * 64 + j * 16 + col][(((ks << 2) | quad) ^ rsw) * 8];
#pragma unroll
      for (int i = 0; i < 4; i++)
#pragma unroll
        for (int j = 0; j < 4; j++)
          acc[i][j] = __builtin_amdgcn_mfma_f32_16x16x32_bf16(af[i], bfr[j], acc[i][j], 0, 0, 0);
    }
  }
  const int f32o = final_out ? (f == 0) : 0;
#pragma unroll
  for (int j = 0; j < 4; j++) {
    int n = n0 + wn * 64 + j * 16 + col;
    float bv = f ? bf2f(((const unsigned short*)bias)[n]) : ((const float*)bias)[n];
#pragma unroll
    for (int i = 0; i < 4; i++)
#pragma unroll
      for (int r = 0; r < 4; r++) {
        int m = m0 + wm * 64 + i * 16 + quad * 4 + r;
        float v = acc[i][j][r] + bv;
        if (f32o) ((float*)Cout)[(size_t)m * N + n] = v;
        else      ((unsigned short*)Cout)[(size_t)m * N + n] = f2bf(v);
      }
  }
}

// ---------- flash attention (causal), paired q-tiles — round-6 winner ----------
// Block x in [0,16) processes qt = 31-x then qt = x  -> 33 iterations per block.
#define ATT_SCALE 0.08838834764831845f  // 1/sqrt(128)
__global__ __launch_bounds__(256) void attn_k(const unsigned short* __restrict__ qkv,
                                              const unsigned short* __restrict__ Vt,
                                              unsigned short* __restrict__ O) {
  __shared__ __attribute__((aligned(16))) unsigned short Ks[64][136];  // [key][d]
  __shared__ __attribute__((aligned(16))) unsigned short Vs[128][72];  // V^T: [d][key]
  __shared__ __attribute__((aligned(16))) unsigned short Ps[4][16][72];
  const int t = threadIdx.x;
  const int wave = t >> 6, lane = t & 63;
  const int col = lane & 15, quad = lane >> 4;
  const int h = blockIdx.y, b = blockIdx.z;
  const size_t base = (size_t)b * 2048 * 6144;
  const size_t vbase = ((size_t)(b * 16 + h)) * 128 * 2048;
  const int hcol = h * 128;

  const int kr = t >> 2;        // K staging: row 0..63
  const int kc = (t & 3) * 8;   // 0/8/16/24
  const int vr = t >> 1;        // V staging: d-row 0..127
  const int vc = (t & 1) * 32;  // 0/32

  const f32x4 fzero = {0.f, 0.f, 0.f, 0.f};

  for (int pass = 0; pass < 2; pass++) {
    const int qt = pass ? (int)blockIdx.x : 31 - (int)blockIdx.x;

    bf16x8 qf[4];  // Q A-fragments
    {
      size_t qrow = base + (size_t)(qt * 64 + wave * 16 + col) * 6144 + hcol;
#pragma unroll
      for (int ks = 0; ks < 4; ks++)
        qf[ks] = *(const bf16x8*)&qkv[qrow + ks * 32 + quad * 8];
    }

    f32x4 o[8];
#pragma unroll
    for (int i = 0; i < 8; i++) o[i] = fzero;
    float l_i[4] = {0.f, 0.f, 0.f, 0.f};

    __syncthreads();  // guard LDS vs previous pass readers
    {
      size_t grow = base + (size_t)kr * 6144 + 2048 + hcol;
#pragma unroll
      for (int p = 0; p < 4; p++)
        *(bf16x8*)&Ks[kr][kc + p * 32] = *(const bf16x8*)&qkv[grow + kc + p * 32];
      size_t vrow = vbase + (size_t)vr * 2048;
#pragma unroll
      for (int c = 0; c < 4; c++)
        *(bf16x8*)&Vs[vr][vc + c * 8] = *(const bf16x8*)&Vt[vrow + vc + c * 8];
    }
    __syncthreads();

    for (int kt = 0; kt <= qt; kt++) {
      bf16x8 kreg[4], vreg[4];
      const bool pf = (kt < qt);
      if (pf) {
        size_t grow = base + (size_t)((kt + 1) * 64 + kr) * 6144 + 2048 + hcol;
#pragma unroll
        for (int p = 0; p < 4; p++)
          kreg[p] = *(const bf16x8*)&qkv[grow + kc + p * 32];
        size_t vrow = vbase + (size_t)vr * 2048 + (kt + 1) * 64;
#pragma unroll
        for (int c = 0; c < 4; c++)
          vreg[c] = *(const bf16x8*)&Vt[vrow + vc + c * 8];
      }

      // S = Q @ K^T
      f32x4 sc[4];
#pragma unroll
      for (int nb = 0; nb < 4; nb++) {
        f32x4 s = fzero;
#pragma unroll
        for (int ks = 0; ks < 4; ks++) {
          bf16x8 kf = *(const bf16x8*)&Ks[nb * 16 + col][ks * 32 + quad * 8];
          s = __builtin_amdgcn_mfma_f32_16x16x32_bf16(qf[ks], kf, s, 0, 0, 0);
        }
        sc[nb] = s;
      }

      const bool diag = (kt == qt);
#pragma unroll
      for (int nb = 0; nb < 4; nb++) {
        int kl = nb * 16 + col;
#pragma unroll
        for (int r = 0; r < 4; r++) {
          float s = sc[nb][r];
          if (diag && kl > wave * 16 + quad * 4 + r) s = -1e30f;
          float p = __expf(s * ATT_SCALE);
          l_i[r] += p;
          Ps[wave][quad * 4 + r][nb * 16 + col] = f2bf(p);
        }
      }
      bf16x8 pfr[2];
#pragma unroll
      for (int ks2 = 0; ks2 < 2; ks2++)
        pfr[ks2] = *(const bf16x8*)&Ps[wave][col][ks2 * 32 + quad * 8];
#pragma unroll
      for (int nbo = 0; nbo < 8; nbo++)
#pragma unroll
        for (int ks2 = 0; ks2 < 2; ks2++) {
          bf16x8 vf = *(const bf16x8*)&Vs[nbo * 16 + col][ks2 * 32 + quad * 8];
          o[nbo] = __builtin_amdgcn_mfma_f32_16x16x32_bf16(pfr[ks2], vf, o[nbo], 0, 0, 0);
        }

      __syncthreads();
      if (pf) {
#pragma unroll
        for (int p = 0; p < 4; p++)
          *(bf16x8*)&Ks[kr][kc + p * 32] = kreg[p];
#pragma unroll
        for (int c = 0; c < 4; c++)
          *(bf16x8*)&Vs[vr][vc + c * 8] = vreg[c];
      }
      __syncthreads();
    }

#pragma unroll
    for (int r = 0; r < 4; r++) {
#pragma unroll
      for (int off = 1; off < 16; off <<= 1)
        l_i[r] += __shfl_xor(l_i[r], off, 64);
      l_i[r] = 1.0f / l_i[r];
    }

#pragma unroll
    for (int nbo = 0; nbo < 8; nbo++)
#pragma unroll
      for (int r = 0; r < 4; r++) {
        int m = qt * 64 + wave * 16 + quad * 4 + r;
        O[((size_t)b * 2048 + m) * 2048 + hcol + nbo * 16 + col] = f2bf(o[nbo][r] * l_i[r]);
      }
  }
}

// ---------- launch ----------
extern "C" void kernel_launch(void* const* d_in, const int* in_sizes, int n_in,
                              void* d_out, int out_size, void* d_ws, size_t ws_size,
                              hipStream_t stream) {
  (void)in_sizes; (void)n_in; (void)out_size; (void)ws_size;
  int* flag = (int*)d_ws;
  unsigned short* wsu = (unsigned short*)d_ws + 128;
  unsigned short* Wt_qkv    = wsu;                                  // 6144*2048
  unsigned short* Wt_proj   = Wt_qkv + (size_t)6144 * 2048;         // 2048*2048
  unsigned short* QKV       = Wt_proj + (size_t)2048 * 2048;        // 4096*6144
  unsigned short* hidden_bf = QKV + (size_t)4096 * 6144;            // 4096*2048
  unsigned short* Obuf      = Wt_qkv;     // alias: dead after QKV gemm
  unsigned short* Vt        = hidden_bf + (size_t)4096 * 2048;      // 2048*... wait — keep distinct

  detect_k<<<1, 256, 0, stream>>>((const unsigned short*)d_in[0], flag);
  cvt_hidden_k<<<2048, 256, 0, stream>>>(d_in[0], hidden_bf, 4096 * 2048, flag);
  transpose_w2_k<<<16384, 256, 0, stream>>>(d_in[1], d_in[3], Wt_qkv, Wt_proj, flag);
  gemm_bias_k<<<dim3(48, 32), 256, 0, stream>>>((const unsigned short*)d_in[0], hidden_bf,
                                                Wt_qkv, d_in[2], QKV,
                                                4096, 6144, 2048, flag, 0);
  transpose_v_k<<<dim3(64, 4, 32), 256, 0, stream>>>(QKV, Vt);
  attn_k<<<dim3(16, 16, 2), 256, 0, stream>>>(QKV, Vt, Obuf);
  gemm_bias_k<<<dim3(16, 32), 256, 0, stream>>>(Obuf, Obuf, Wt_proj, d_in[4], d_out,
                                                4096, 2048, 2048, flag, 1);
}